// Round 2
// baseline (98.550 us; speedup 1.0000x reference)
//
#include <hip/hip_runtime.h>
#include <hip/hip_bf16.h>
#include <math.h>

#define D_FEAT 64
#define N_ETYPES 8
#define EPS_F 1e-8f

// ---------------------------------------------------------------------------
// Kernel 1: per-node pass. 16 lanes per node, float4 per lane (64 floats/row).
//   - out row   = feat row (bit-exact copy; also zero-init for zero rows,
//                 which are the accumulation targets of the edge pass)
//   - mask[n]   = (sum|feat| == 0) ? 0 : 1
//   - nw_exp[n] = mask * exp(feat . attn)        (TEMPERATURE == 1)
//   - nw_exp_sum[n] = 0
// ---------------------------------------------------------------------------
__global__ void node_kernel(const float* __restrict__ feat,
                            const float* __restrict__ attn,
                            float* __restrict__ out,
                            float* __restrict__ nw_exp,
                            float* __restrict__ nw_exp_sum,
                            int* __restrict__ mask,
                            int N) {
    int gid  = blockIdx.x * blockDim.x + threadIdx.x;
    int node = gid >> 4;          // 16 lanes per node row
    int sub  = gid & 15;          // this lane's float4 within the row
    if (node >= N) return;

    const float4 f = ((const float4*)feat)[(size_t)node * 16 + sub];
    const float4 a = ((const float4*)attn)[sub];

    // out = feat (bit-exact; final value for nonzero rows, zero-init otherwise)
    ((float4*)out)[(size_t)node * 16 + sub] = f;

    float abss = fabsf(f.x) + fabsf(f.y) + fabsf(f.z) + fabsf(f.w);
    float dot  = f.x * a.x + f.y * a.y + f.z * a.z + f.w * a.w;

    // reduce across the 16-lane group (xor offsets < 16 stay inside the group)
    #pragma unroll
    for (int off = 1; off < 16; off <<= 1) {
        abss += __shfl_xor(abss, off);
        dot  += __shfl_xor(dot,  off);
    }

    if (sub == 0) {
        int m = (abss == 0.0f) ? 0 : 1;
        mask[node]       = m;
        nw_exp[node]     = m ? expf(dot) : 0.0f;
        nw_exp_sum[node] = 0.0f;
    }
}

// ---------------------------------------------------------------------------
// Kernel 2: edge pass. Per-edge early exit on mask[dst] != 0 (dst keeps its
// original features). For the rare unmasked destinations, accumulate directly
// into out[dst] (pre-zeroed by the feat copy). The per-edge-type weight
// (edge_weight[t,:] . edge_weight_param + 1) is computed inline — 8 L2-cached
// FMAs — only on the unmasked path, so no prep kernel / table is needed.
// ---------------------------------------------------------------------------
__global__ void edge_kernel(const int* __restrict__ src,
                            const int* __restrict__ dst,
                            const int* __restrict__ e_feat,
                            const float* __restrict__ feat,
                            const float* __restrict__ nw_exp,
                            const int* __restrict__ mask,
                            const float* __restrict__ edge_weight,
                            const float* __restrict__ edge_weight_param,
                            float* __restrict__ out,
                            float* __restrict__ nw_exp_sum,
                            int E) {
    int e = blockIdx.x * blockDim.x + threadIdx.x;
    if (e >= E) return;
    int d = dst[e];               // coalesced 4 B/lane
    if (mask[d] != 0) return;     // mask is 400 KB -> L2-resident gather
    int s = src[e];
    float w = nw_exp[s];          // already 0 for zero-mask sources
    atomicAdd(&nw_exp_sum[d], w);
    int t = e_feat[e] - 1;
    float ewv = 1.0f;
    #pragma unroll
    for (int j = 0; j < N_ETYPES; ++j)
        ewv += edge_weight[t * N_ETYPES + j] * edge_weight_param[j];
    float scale = w * ewv;
    const float* fs = feat + (size_t)s * D_FEAT;
    float*       od = out  + (size_t)d * D_FEAT;
    #pragma unroll 4
    for (int k = 0; k < D_FEAT; ++k)
        atomicAdd(&od[k], fs[k] * scale);
}

// ---------------------------------------------------------------------------
// Kernel 3: fixup — divide unmasked rows by denom. Per-node early exit.
// ---------------------------------------------------------------------------
__global__ void fixup_kernel(float* __restrict__ out,
                             const float* __restrict__ nw_exp_sum,
                             const int* __restrict__ mask,
                             int N) {
    int n = blockIdx.x * blockDim.x + threadIdx.x;
    if (n >= N || mask[n] != 0) return;
    float s = nw_exp_sum[n];
    float denom = (s < EPS_F) ? 1.0f : s;
    float* row = out + (size_t)n * D_FEAT;
    #pragma unroll 4
    for (int k = 0; k < D_FEAT; ++k)
        row[k] = row[k] / denom;
}

extern "C" void kernel_launch(void* const* d_in, const int* in_sizes, int n_in,
                              void* d_out, int out_size, void* d_ws, size_t ws_size,
                              hipStream_t stream) {
    const float* feat              = (const float*)d_in[0];
    const float* attn              = (const float*)d_in[1];
    const float* edge_weight       = (const float*)d_in[2];
    const float* edge_weight_param = (const float*)d_in[3];
    const int*   src               = (const int*)d_in[4];
    const int*   dst               = (const int*)d_in[5];
    const int*   e_feat            = (const int*)d_in[6];
    float*       out               = (float*)d_out;

    const int N = in_sizes[0] / D_FEAT;
    const int E = in_sizes[4];

    // workspace layout (~1.2 MB): nw_exp[N] | nw_exp_sum[N] | mask[N]
    float* nw_exp     = (float*)d_ws;
    float* nw_exp_sum = nw_exp + N;
    int*   mask       = (int*)(nw_exp_sum + N);

    const int threadsA = 256;
    const int nodesPerBlock = threadsA / 16;   // 16 lanes per node
    node_kernel<<<(N + nodesPerBlock - 1) / nodesPerBlock, threadsA, 0, stream>>>(
        feat, attn, out, nw_exp, nw_exp_sum, mask, N);

    edge_kernel<<<(E + 255) / 256, 256, 0, stream>>>(
        src, dst, e_feat, feat, nw_exp, mask, edge_weight, edge_weight_param,
        out, nw_exp_sum, E);

    fixup_kernel<<<(N + 255) / 256, 256, 0, stream>>>(
        out, nw_exp_sum, mask, N);
}

// Round 3
// 96.667 us; speedup vs baseline: 1.0195x; 1.0195x over previous
//
#include <hip/hip_runtime.h>
#include <hip/hip_bf16.h>
#include <math.h>

#define D_FEAT 64
#define N_ETYPES 8
#define EPS_F 1e-8f

typedef float v4f __attribute__((ext_vector_type(4)));

// ---------------------------------------------------------------------------
// Kernel 1: per-node pass. 16 lanes per node, float4 per lane (64 floats/row).
//   - out row   = feat row (bit-exact copy; also zero-init for zero rows,
//                 which are the accumulation targets of the edge pass)
//   - side[n]   = { nw_exp = mask*exp(feat.attn), 0 (sum init), mask, 0 }
//   - flag = 1 iff some zero row exists.
// Gating note: edge/fixup run their full (per-element-checked) path iff
// *flag == 1. Node only ever writes 1. Any pre-existing flag value is safe:
//   garbage != 1 && zero row exists  -> node writes 1 -> edge runs (correct)
//   garbage == 1 && no zero row      -> edge runs, per-edge mask check no-ops
// So no flag initialization is needed (ws arrives poisoned 0xAA).
// ---------------------------------------------------------------------------
__global__ void node_kernel(const float* __restrict__ feat,
                            const float* __restrict__ attn,
                            float* __restrict__ out,
                            v4f* __restrict__ side,
                            int* __restrict__ flag,
                            int N) {
    int gid  = blockIdx.x * blockDim.x + threadIdx.x;
    int node = gid >> 4;          // 16 lanes per node row
    int sub  = gid & 15;          // this lane's float4 within the row
    if (node >= N) return;

    const v4f f = __builtin_nontemporal_load(((const v4f*)feat) + (size_t)node * 16 + sub);
    const v4f a = ((const v4f*)attn)[sub];   // cached, reused by every block

    // out = feat (bit-exact; final value for nonzero rows, zero-init otherwise).
    // Nontemporal: this stream is never re-read in the steady (flag!=1) state.
    __builtin_nontemporal_store(f, ((v4f*)out) + (size_t)node * 16 + sub);

    float abss = fabsf(f.x) + fabsf(f.y) + fabsf(f.z) + fabsf(f.w);
    float dot  = f.x * a.x + f.y * a.y + f.z * a.z + f.w * a.w;

    // reduce across the 16-lane group (xor offsets < 16 stay inside the group)
    #pragma unroll
    for (int off = 1; off < 16; off <<= 1) {
        abss += __shfl_xor(abss, off);
        dot  += __shfl_xor(dot,  off);
    }

    if (sub == 0) {
        float m = (abss == 0.0f) ? 0.0f : 1.0f;
        v4f s;
        s.x = (m != 0.0f) ? expf(dot) : 0.0f;  // nw_exp (TEMPERATURE == 1)
        s.y = 0.0f;                             // nw_exp_sum accumulator init
        s.z = m;                                // mask
        s.w = 0.0f;
        side[node] = s;    // lanes 0/16/32/48 of a wave -> contiguous 64 B
        if (m == 0.0f) *flag = 1;
    }
}

// ---------------------------------------------------------------------------
// Kernel 2: edge pass — full path only when a zero row exists. Accumulates
// directly into out[dst] (pre-zeroed by the feat copy). The per-edge-type
// weight (edge_weight[t,:].edge_weight_param + 1) is computed inline on the
// rare path only.
// ---------------------------------------------------------------------------
__global__ void edge_kernel(const int* __restrict__ src,
                            const int* __restrict__ dst,
                            const int* __restrict__ e_feat,
                            const float* __restrict__ feat,
                            v4f* __restrict__ side,
                            const float* __restrict__ edge_weight,
                            const float* __restrict__ edge_weight_param,
                            const int* __restrict__ flag,
                            float* __restrict__ out,
                            int E) {
    if (*flag != 1) return;   // steady state: one L2-hit load per block, exit
    int stride = gridDim.x * blockDim.x;
    for (int e = blockIdx.x * blockDim.x + threadIdx.x; e < E; e += stride) {
        int d = dst[e];
        if (side[d].z != 0.0f) continue;  // dst keeps its original features
        int s = src[e];
        float w = side[s].x;              // nw_exp (0 for zero-mask sources)
        atomicAdd(&((float*)&side[d])[1], w);   // nw_exp_sum
        int t = e_feat[e] - 1;
        float ewv = 1.0f;
        #pragma unroll
        for (int j = 0; j < N_ETYPES; ++j)
            ewv += edge_weight[t * N_ETYPES + j] * edge_weight_param[j];
        float scale = w * ewv;
        const float* fs = feat + (size_t)s * D_FEAT;
        float*       od = out  + (size_t)d * D_FEAT;
        #pragma unroll 4
        for (int k = 0; k < D_FEAT; ++k)
            atomicAdd(&od[k], fs[k] * scale);
    }
}

// ---------------------------------------------------------------------------
// Kernel 3: fixup — divide zero-mask rows by denom. Same gate as edge pass.
// ---------------------------------------------------------------------------
__global__ void fixup_kernel(float* __restrict__ out,
                             const v4f* __restrict__ side,
                             const int* __restrict__ flag,
                             int N) {
    if (*flag != 1) return;
    int stride = gridDim.x * blockDim.x;
    for (int n = blockIdx.x * blockDim.x + threadIdx.x; n < N; n += stride) {
        v4f s = side[n];
        if (s.z != 0.0f) continue;
        float denom = (s.y < EPS_F) ? 1.0f : s.y;
        float* row = out + (size_t)n * D_FEAT;
        #pragma unroll 4
        for (int k = 0; k < D_FEAT; ++k)
            row[k] = row[k] / denom;   // keep exact reference order (ft/denom)
    }
}

extern "C" void kernel_launch(void* const* d_in, const int* in_sizes, int n_in,
                              void* d_out, int out_size, void* d_ws, size_t ws_size,
                              hipStream_t stream) {
    const float* feat              = (const float*)d_in[0];
    const float* attn              = (const float*)d_in[1];
    const float* edge_weight       = (const float*)d_in[2];
    const float* edge_weight_param = (const float*)d_in[3];
    const int*   src               = (const int*)d_in[4];
    const int*   dst               = (const int*)d_in[5];
    const int*   e_feat            = (const int*)d_in[6];
    float*       out               = (float*)d_out;

    const int N = in_sizes[0] / D_FEAT;
    const int E = in_sizes[4];

    // workspace layout (~1.6 MB): side[N] (float4) | flag
    v4f* side = (v4f*)d_ws;
    int* flag = (int*)(side + N);

    const int threadsA = 256;
    const int nodesPerBlock = threadsA / 16;   // 16 lanes per node
    node_kernel<<<(N + nodesPerBlock - 1) / nodesPerBlock, threadsA, 0, stream>>>(
        feat, attn, out, side, flag, N);

    // Gated kernels: modest grid-stride grids so the (always-taken) gated
    // exit costs only dispatch time; full path still covers all E / N.
    edge_kernel<<<1024, 256, 0, stream>>>(
        src, dst, e_feat, feat, side, edge_weight, edge_weight_param,
        flag, out, E);

    fixup_kernel<<<512, 256, 0, stream>>>(out, side, flag, N);
}

// Round 4
// 94.131 us; speedup vs baseline: 1.0469x; 1.0269x over previous
//
#include <hip/hip_runtime.h>
#include <hip/hip_bf16.h>
#include <math.h>

#define D_FEAT 64
#define N_ETYPES 8
#define EPS_F 1e-8f

typedef float v4f __attribute__((ext_vector_type(4)));

// ---------------------------------------------------------------------------
// Kernel 1: per-node pass. 16 lanes per node, float4 per lane (64 floats/row).
//   - out row   = feat row (bit-exact copy; also the zero-init of the rare
//                 path's accumulation target, since a zero row copies zeros)
//   - side[n]   = { nw_exp = mask*exp(feat.attn), 0 (sum init), mask, 0 }
//   - flag = 1 iff some all-zero feature row exists
//   - counter = 0 (rare-path completion barrier; stream order guarantees this
//                  is visible before the finish kernel runs)
// Gating note: finish kernel runs its full path iff *flag == 1; node only
// ever writes 1. Any pre-existing (poisoned) flag value is safe:
//   poison != 1 && zero row exists -> node writes 1 -> finish runs (correct)
//   poison == 1 && no zero row     -> finish runs, per-element checks no-op
// ---------------------------------------------------------------------------
__global__ void node_kernel(const float* __restrict__ feat,
                            const float* __restrict__ attn,
                            float* __restrict__ out,
                            v4f* __restrict__ side,
                            int* __restrict__ flag,
                            int* __restrict__ counter,
                            int N) {
    int gid  = blockIdx.x * blockDim.x + threadIdx.x;
    int node = gid >> 4;          // 16 lanes per node row
    int sub  = gid & 15;          // this lane's float4 within the row
    if (gid == 0) *counter = 0;   // init rare-path barrier (ws is poisoned)
    if (node >= N) return;

    const v4f f = __builtin_nontemporal_load(((const v4f*)feat) + (size_t)node * 16 + sub);
    const v4f a = ((const v4f*)attn)[sub];   // cached, reused by every block

    // out = feat (bit-exact; final value for nonzero rows, zero-init otherwise)
    __builtin_nontemporal_store(f, ((v4f*)out) + (size_t)node * 16 + sub);

    float abss = fabsf(f.x) + fabsf(f.y) + fabsf(f.z) + fabsf(f.w);
    float dot  = f.x * a.x + f.y * a.y + f.z * a.z + f.w * a.w;

    // reduce across the 16-lane group (xor offsets < 16 stay inside the group)
    #pragma unroll
    for (int off = 1; off < 16; off <<= 1) {
        abss += __shfl_xor(abss, off);
        dot  += __shfl_xor(dot,  off);
    }

    if (sub == 0) {
        float m = (abss == 0.0f) ? 0.0f : 1.0f;
        v4f s;
        s.x = (m != 0.0f) ? expf(dot) : 0.0f;  // nw_exp (TEMPERATURE == 1)
        s.y = 0.0f;                             // nw_exp_sum accumulator init
        s.z = m;                                // mask
        s.w = 0.0f;
        side[node] = s;    // lanes 0/16/32/48 of a wave -> contiguous 64 B
        if (m == 0.0f) *flag = 1;
    }
}

// ---------------------------------------------------------------------------
// Kernel 2: gated finish — edge aggregation + denom fixup in one launch.
// Steady state (*flag != 1): every block exits after one L2-hit word load.
// Rare path (some zero row exists):
//   phase 1: grid-stride over edges; for unmasked dst, accumulate
//            nw_exp[src] into side[dst].y and nw_exp[src]*ew*feat[src]
//            into out[dst] (pre-zeroed by the feat copy).
//   phase 2: block-completion barrier via counter; the LAST block divides
//            every unmasked row by denom. Slow (one block) but correct, and
//            only ever taken when an all-zero feature row exists.
// ---------------------------------------------------------------------------
__global__ void finish_kernel(const int* __restrict__ src,
                              const int* __restrict__ dst,
                              const int* __restrict__ e_feat,
                              const float* __restrict__ feat,
                              v4f* __restrict__ side,
                              const float* __restrict__ edge_weight,
                              const float* __restrict__ edge_weight_param,
                              const int* __restrict__ flag,
                              int* __restrict__ counter,
                              float* __restrict__ out,
                              int E, int N) {
    if (*flag != 1) return;   // steady state: exit immediately

    // ---- phase 1: edge accumulation (grid-stride) ----
    int stride = gridDim.x * blockDim.x;
    for (int e = blockIdx.x * blockDim.x + threadIdx.x; e < E; e += stride) {
        int d = dst[e];
        if (side[d].z != 0.0f) continue;  // dst keeps its original features
        int s = src[e];
        float w = side[s].x;              // nw_exp (0 for zero-mask sources)
        atomicAdd(&((float*)&side[d])[1], w);   // nw_exp_sum
        int t = e_feat[e] - 1;
        float ewv = 1.0f;
        #pragma unroll
        for (int j = 0; j < N_ETYPES; ++j)
            ewv += edge_weight[t * N_ETYPES + j] * edge_weight_param[j];
        float scale = w * ewv;
        const float* fs = feat + (size_t)s * D_FEAT;
        float*       od = out  + (size_t)d * D_FEAT;
        #pragma unroll 4
        for (int k = 0; k < D_FEAT; ++k)
            atomicAdd(&od[k], fs[k] * scale);
    }

    // ---- phase 2: completion barrier; last block does the fixup ----
    __threadfence();              // order this block's atomics before signal
    __syncthreads();
    __shared__ int is_last;
    if (threadIdx.x == 0) {
        int old = atomicAdd(counter, 1);
        is_last = (old == (int)gridDim.x - 1) ? 1 : 0;
    }
    __syncthreads();
    if (!is_last) return;
    __threadfence();              // acquire other blocks' accumulations

    for (int n = threadIdx.x; n < N; n += blockDim.x) {
        v4f s = side[n];
        if (s.z != 0.0f) continue;
        float denom = (s.y < EPS_F) ? 1.0f : s.y;
        float* row = out + (size_t)n * D_FEAT;
        #pragma unroll 4
        for (int k = 0; k < D_FEAT; ++k)
            row[k] = row[k] / denom;   // keep exact reference order (ft/denom)
    }
}

extern "C" void kernel_launch(void* const* d_in, const int* in_sizes, int n_in,
                              void* d_out, int out_size, void* d_ws, size_t ws_size,
                              hipStream_t stream) {
    const float* feat              = (const float*)d_in[0];
    const float* attn              = (const float*)d_in[1];
    const float* edge_weight       = (const float*)d_in[2];
    const float* edge_weight_param = (const float*)d_in[3];
    const int*   src               = (const int*)d_in[4];
    const int*   dst               = (const int*)d_in[5];
    const int*   e_feat            = (const int*)d_in[6];
    float*       out               = (float*)d_out;

    const int N = in_sizes[0] / D_FEAT;
    const int E = in_sizes[4];

    // workspace layout (~1.6 MB): side[N] (float4) | flag | counter
    v4f* side    = (v4f*)d_ws;
    int* flag    = (int*)(side + N);
    int* counter = flag + 1;

    const int threadsA = 256;
    const int nodesPerBlock = threadsA / 16;   // 16 lanes per node
    node_kernel<<<(N + nodesPerBlock - 1) / nodesPerBlock, threadsA, 0, stream>>>(
        feat, attn, out, side, flag, counter, N);

    // Gated finish: small grid -> steady-state cost is just dispatch + one
    // cached word per block; rare path covers all E via grid-stride.
    finish_kernel<<<256, 256, 0, stream>>>(
        src, dst, e_feat, feat, side, edge_weight, edge_weight_param,
        flag, counter, out, E, N);
}